// Round 1
// baseline (11910.797 us; speedup 1.0000x reference)
//
#include <hip/hip_runtime.h>
#include <hip/hip_bf16.h>

#define NN 4096
#define DD 128
#define BB 128
#define QQ 5
#define MAXDEG 96
#define ZPAD 132   // 128 + 4 pad: rows start 4 banks apart -> conflict-free 4-row float4 reads

__device__ __forceinline__ float dot4f(float4 a, float4 b) {
    return a.x*b.x + a.y*b.y + a.z*b.z + a.w*b.w;
}

// ---------------- neighbor-list precompute (fully parallel, deterministic) ----------------
__global__ void nbr_kernel(const int* __restrict__ u, const int* __restrict__ v,
                           const float* __restrict__ A, const float* __restrict__ S,
                           int* __restrict__ nbr_cnt, int* __restrict__ nbr_idx,
                           float* __restrict__ nbr_q)
{
    __shared__ int   lcnt[257];
    __shared__ int   sidx[MAXDEG];
    __shared__ float sq[MAXDEG];
    __shared__ float ssum;
    __shared__ int   stot;

    const int p    = blockIdx.x;          // 0..255 : (event i, side)
    const int i    = p >> 1;
    const int side = p & 1;
    const int other = (side == 0) ? v[i] : u[i];   // h_struct[0]=agg(v), h_struct[1]=agg(u)
    const float* Arow = A + (size_t)other * NN;
    const float* Srow = S + (size_t)other * NN;
    const int tid = threadIdx.x;          // 0..255

    // deterministic compaction: contiguous 16-elem range per thread + exclusive scan
    const int base = tid * 16;
    int c0 = 0;
    for (int j = 0; j < 16; ++j) c0 += (Arow[base + j] > 0.0f) ? 1 : 0;
    lcnt[tid] = c0;
    __syncthreads();
    if (tid == 0) {
        int s = 0;
        for (int k = 0; k < 256; ++k) { int c = lcnt[k]; lcnt[k] = s; s += c; }
        stot = s;
    }
    __syncthreads();
    int off = lcnt[tid];
    for (int j = 0; j < 16; ++j) {
        if (Arow[base + j] > 0.0f) {
            if (off < MAXDEG) sidx[off] = base + j;
            ++off;
        }
    }
    __syncthreads();
    int cnt = stot; if (cnt > MAXDEG) cnt = MAXDEG;
    for (int jj = tid; jj < cnt; jj += 256) sq[jj] = expf(Srow[sidx[jj]]);
    __syncthreads();
    if (tid == 0) {
        float s = 0.0f;
        for (int jj = 0; jj < cnt; ++jj) s += sq[jj];
        ssum = s + 1e-7f;
    }
    __syncthreads();
    for (int jj = tid; jj < cnt; jj += 256) {
        nbr_q[p * MAXDEG + jj]   = sq[jj] / ssum;
        nbr_idx[p * MAXDEG + jj] = sidx[jj];
    }
    if (tid == 0) nbr_cnt[p] = cnt;
}

// ---------------- sequential scan: 1 block, 512 threads ----------------
__global__ __launch_bounds__(512, 2) void scan_kernel(
    const int* __restrict__ u, const int* __restrict__ v,
    const float* __restrict__ time_diff, const int* __restrict__ neg,
    float* __restrict__ z,
    const int* __restrict__ nbr_cnt, const int* __restrict__ nbr_idx, const float* __restrict__ nbr_q,
    const float* __restrict__ Wh,  const float* __restrict__ bh,
    const float* __restrict__ Wst, const float* __restrict__ bst,
    const float* __restrict__ Wrc, const float* __restrict__ brc,
    const float* __restrict__ Wt,  const float* __restrict__ bt,
    float* __restrict__ ZU, float* __restrict__ ZV,
    float* __restrict__ UN, float* __restrict__ VN)
{
    __shared__ float zs[MAXDEG][ZPAD];
    __shared__ float zu_s[DD], zv_s[DD];
    __shared__ float h_s[2][DD];
    __shared__ float zupd_s[2][DD];
    __shared__ float q_s[MAXDEG];
    __shared__ float tdi_s[8];

    const int t   = threadIdx.x;
    const int d4  = t >> 2;       // output dim 0..127
    const int rep = t & 3;        // 4 lanes cooperate per dim (same wave, contiguous)

    // persistent register-resident weights
    float4 whrow[32];             // W_h row d4 (128 f32)
    #pragma unroll
    for (int m = 0; m < 32; ++m) whrow[m] = *(const float4*)(Wh + (size_t)d4*DD + m*4);
    float4 wst[8], wrc4[8];       // k-slices [rep*32, rep*32+32) of W_struct/W_rec row d4
    #pragma unroll
    for (int m = 0; m < 8; ++m) {
        wst[m]  = *(const float4*)(Wst + (size_t)d4*DD + rep*32 + m*4);
        wrc4[m] = *(const float4*)(Wrc + (size_t)d4*DD + rep*32 + m*4);
    }
    const float4 wt_r  = *(const float4*)(Wt + (size_t)d4*4);
    const float  bh_r  = bh[d4];
    const float  bsum_r = bst[d4] + brc[d4] + bt[d4];

    auto agg_side = [&](int side, int cnt) {
        float mx = -3.0e38f;
        for (int j = rep; j < cnt; j += 4) {
            const float4* zr = (const float4*)&zs[j][0];
            float a0=0.f, a1=0.f, a2=0.f, a3=0.f;
            #pragma unroll
            for (int m = 0; m < 32; m += 4) {
                a0 += dot4f(zr[m+0], whrow[m+0]);
                a1 += dot4f(zr[m+1], whrow[m+1]);
                a2 += dot4f(zr[m+2], whrow[m+2]);
                a3 += dot4f(zr[m+3], whrow[m+3]);
            }
            const float acc = (a0 + a1) + (a2 + a3);
            mx = fmaxf(mx, q_s[j] * (acc + bh_r));
        }
        mx = fmaxf(mx, __shfl_xor(mx, 1));
        mx = fmaxf(mx, __shfl_xor(mx, 2));
        if (rep == 0) h_s[side][d4] = (cnt > 0) ? (1.0f / (1.0f + expf(-mx))) : 0.0f;
    };

    for (int i = 0; i < BB; ++i) {
        const int ui = u[i];
        const int vi = v[i];
        const int p0 = i * 2;
        const int cnt0 = nbr_cnt[p0];      // side 0 : neighbors of v[i]
        const int cnt1 = nbr_cnt[p0 + 1];  // side 1 : neighbors of u[i]

        // ---- P0: all reads of this step's pre-update z; stage side 0 ----
        if (t < DD) {
            float val = z[(size_t)ui*DD + t];
            zu_s[t] = val; ZU[(size_t)i*DD + t] = val;
        } else if (t < 2*DD) {
            int c = t - DD;
            float val = z[(size_t)vi*DD + c];
            zv_s[c] = val; ZV[(size_t)i*DD + c] = val;
        }
        if (t < 8) {
            const float sd[4] = {50.f, 7.f, 15.f, 15.f};
            tdi_s[t] = time_diff[i*8 + t] / sd[t & 3];
        }
        if (t < cnt0) q_s[t] = nbr_q[(size_t)p0*MAXDEG + t];
        // negative-sample gather (pre-update z)
        for (int e = t; e < 2*QQ*DD; e += 512) {
            int k = e >> 7, c = e & 127;
            int nd = neg[i*2*QQ + k];
            float val = z[(size_t)nd*DD + c];
            if (k < QQ) VN[((size_t)i*2*QQ + k)*DD + c] = val;
            else        UN[((size_t)i*2*QQ + k)*DD + c] = val;
        }
        // broadcast rows: UN[0..Q-1]=zu, VN[Q..2Q-1]=zv
        for (int e = t; e < QQ*DD; e += 512) {
            int k = e >> 7, c = e & 127;
            UN[((size_t)i*2*QQ + k)*DD + c]        = z[(size_t)ui*DD + c];
            VN[((size_t)i*2*QQ + QQ + k)*DD + c]   = z[(size_t)vi*DD + c];
        }
        // stage side-0 neighbor rows
        for (int e = t; e < cnt0*DD; e += 512) {
            int rr = e >> 7, c = e & 127;
            int row = nbr_idx[(size_t)p0*MAXDEG + rr];
            zs[rr][c] = z[(size_t)row*DD + c];
        }
        __syncthreads();

        // ---- P1: agg side 0 -> h_s[0] ----
        agg_side(0, cnt0);
        __syncthreads();

        // ---- P2: stage side 1 ----
        if (t < cnt1) q_s[t] = nbr_q[(size_t)(p0+1)*MAXDEG + t];
        for (int e = t; e < cnt1*DD; e += 512) {
            int rr = e >> 7, c = e & 127;
            int row = nbr_idx[(size_t)(p0+1)*MAXDEG + rr];
            zs[rr][c] = z[(size_t)row*DD + c];
        }
        __syncthreads();

        // ---- P3: agg side 1 -> h_s[1] ----
        agg_side(1, cnt1);
        __syncthreads();

        // ---- P4: z_upd (2 rows x 128 dims) ----
        {
            float pr[2];
            #pragma unroll
            for (int r = 0; r < 2; ++r) {
                const float* hp = h_s[r];
                const float* zp = (r == 0) ? zu_s : zv_s;
                float a0 = 0.f, a1 = 0.f;
                #pragma unroll
                for (int m = 0; m < 8; ++m) {
                    float4 hh = *(const float4*)&hp[rep*32 + m*4];
                    float4 zz = *(const float4*)&zp[rep*32 + m*4];
                    a0 += dot4f(hh, wst[m]);
                    a1 += dot4f(zz, wrc4[m]);
                }
                float ps = a0 + a1;
                ps += __shfl_xor(ps, 1);
                ps += __shfl_xor(ps, 2);
                const float tdr = tdi_s[r*4+0]*wt_r.x + tdi_s[r*4+1]*wt_r.y
                                + tdi_s[r*4+2]*wt_r.z + tdi_s[r*4+3]*wt_r.w;
                pr[r] = 1.0f / (1.0f + expf(-(ps + bsum_r + tdr)));
            }
            if (rep == 0) { zupd_s[0][d4] = pr[0]; zupd_s[1][d4] = pr[1]; }
        }
        __syncthreads();

        // ---- P5: scatter updates (vi wins if ui==vi, same-thread ordering) ----
        if (t < DD) {
            float a = zupd_s[0][t];
            float b = zupd_s[1][t];
            z[(size_t)ui*DD + t] = a;
            z[(size_t)vi*DD + t] = b;
        }
        __threadfence();   // drain stores + invalidate L1 so next step's reads are fresh
        __syncthreads();
    }
}

// ---------------- intensity epilogue (parallel) ----------------
__global__ void lam_kernel(const float* __restrict__ ZU, const float* __restrict__ ZV,
                           const float* __restrict__ UN, const float* __restrict__ VN,
                           const int* __restrict__ et,
                           const float* __restrict__ w0, const float* __restrict__ b0,
                           const float* __restrict__ w1, const float* __restrict__ b1,
                           const float* __restrict__ psi,
                           float* __restrict__ out)
{
    const int b   = blockIdx.x;            // 0..1407
    const int i   = b / 11;
    const int col = b % 11;
    const int l   = threadIdx.x;           // 0..63
    const float* xu;
    const float* xv;
    if (col == 0) { xu = ZU + (size_t)i*DD; xv = ZV + (size_t)i*DD; }
    else {
        int k = col - 1;
        xu = UN + ((size_t)i*2*QQ + k)*DD;
        xv = VN + ((size_t)i*2*QQ + k)*DD;
    }
    float g0 = xu[l]*w0[l] + xu[l+64]*w0[l+64] + xv[l]*w0[DD+l] + xv[l+64]*w0[DD+l+64];
    float g1 = xu[l]*w1[l] + xu[l+64]*w1[l+64] + xv[l]*w1[DD+l] + xv[l+64]*w1[DD+l+64];
    #pragma unroll
    for (int s = 32; s >= 1; s >>= 1) { g0 += __shfl_xor(g0, s); g1 += __shfl_xor(g1, s); }
    if (l == 0) {
        g0 += b0[0]; g1 += b1[0];
        const float p0 = psi[0], p1 = psi[1];
        float r;
        if (col == 0) {
            int e = et[i];
            float g = e ? g1 : g0;
            float p = e ? p1 : p0;
            float y = g / (p + 1e-7f);
            r = p * (fmaxf(y, 0.f) + log1pf(expf(-fabsf(y))));
        } else {
            float y0 = g0 / (p0 + 1e-7f);
            float y1 = g1 / (p1 + 1e-7f);
            r = p0 * (fmaxf(y0, 0.f) + log1pf(expf(-fabsf(y0))))
              + p1 * (fmaxf(y1, 0.f) + log1pf(expf(-fabsf(y1))));
        }
        out[i*11 + col] = r;
    }
}

extern "C" void kernel_launch(void* const* d_in, const int* in_sizes, int n_in,
                              void* d_out, int out_size, void* d_ws, size_t ws_size,
                              hipStream_t stream)
{
    const int*   u   = (const int*)d_in[0];
    const int*   v   = (const int*)d_in[1];
    const int*   et  = (const int*)d_in[2];
    const float* td  = (const float*)d_in[3];
    const int*   neg = (const int*)d_in[4];
    const float* z0  = (const float*)d_in[5];
    const float* A   = (const float*)d_in[6];
    const float* S   = (const float*)d_in[7];
    const float* w0  = (const float*)d_in[8];
    const float* b0  = (const float*)d_in[9];
    const float* w1  = (const float*)d_in[10];
    const float* b1  = (const float*)d_in[11];
    const float* psi = (const float*)d_in[12];
    const float* Wh  = (const float*)d_in[13];
    const float* bh  = (const float*)d_in[14];
    const float* Wst = (const float*)d_in[15];
    const float* bst = (const float*)d_in[16];
    const float* Wrc = (const float*)d_in[17];
    const float* brc = (const float*)d_in[18];
    const float* Wt  = (const float*)d_in[19];
    const float* bt  = (const float*)d_in[20];

    char* ws = (char*)d_ws;
    size_t off = 0;
    auto alloc = [&](size_t bytes) {
        void* p = ws + off;
        off = (off + bytes + 255) & ~(size_t)255;
        return p;
    };
    float* z    = (float*)alloc((size_t)NN*DD*sizeof(float));
    float* ZU   = (float*)alloc((size_t)BB*DD*sizeof(float));
    float* ZV   = (float*)alloc((size_t)BB*DD*sizeof(float));
    float* UN   = (float*)alloc((size_t)BB*2*QQ*DD*sizeof(float));
    float* VN   = (float*)alloc((size_t)BB*2*QQ*DD*sizeof(float));
    int*   ncnt = (int*)alloc((size_t)2*BB*sizeof(int));
    int*   nidx = (int*)alloc((size_t)2*BB*MAXDEG*sizeof(int));
    float* nq   = (float*)alloc((size_t)2*BB*MAXDEG*sizeof(float));

    hipMemcpyAsync(z, z0, (size_t)NN*DD*sizeof(float), hipMemcpyDeviceToDevice, stream);
    nbr_kernel<<<2*BB, 256, 0, stream>>>(u, v, A, S, ncnt, nidx, nq);
    scan_kernel<<<1, 512, 0, stream>>>(u, v, td, neg, z, ncnt, nidx, nq,
                                       Wh, bh, Wst, bst, Wrc, brc, Wt, bt,
                                       ZU, ZV, UN, VN);
    lam_kernel<<<BB*(1 + 2*QQ), 64, 0, stream>>>(ZU, ZV, UN, VN, et,
                                                 w0, b0, w1, b1, psi, (float*)d_out);
}

// Round 2
// 3220.621 us; speedup vs baseline: 3.6983x; 3.6983x over previous
//
#include <hip/hip_runtime.h>
#include <hip/hip_bf16.h>

#define NN 4096
#define DD 128
#define BB 128
#define QQ 5
#define MAXDEG 96
#define ZROW 144   // 4 k-slices * 36 floats: rep-slices land on distinct bank groups

__device__ __forceinline__ float dot4f(float4 a, float4 b) {
    return a.x*b.x + a.y*b.y + a.z*b.z + a.w*b.w;
}

// ---------------- neighbor-list precompute (fully parallel, deterministic) ----------------
__global__ void nbr_kernel(const int* __restrict__ u, const int* __restrict__ v,
                           const float* __restrict__ A, const float* __restrict__ S,
                           int* __restrict__ nbr_cnt, int* __restrict__ nbr_idx,
                           float* __restrict__ nbr_q)
{
    __shared__ int   lcnt[257];
    __shared__ int   sidx[MAXDEG];
    __shared__ float sq[MAXDEG];
    __shared__ float ssum;
    __shared__ int   stot;

    const int p    = blockIdx.x;          // 0..255 : (event i, side)
    const int i    = p >> 1;
    const int side = p & 1;
    const int other = (side == 0) ? v[i] : u[i];   // h_struct[0]=agg(v), h_struct[1]=agg(u)
    const float* Arow = A + (size_t)other * NN;
    const float* Srow = S + (size_t)other * NN;
    const int tid = threadIdx.x;          // 0..255

    const int base = tid * 16;
    int c0 = 0;
    for (int j = 0; j < 16; ++j) c0 += (Arow[base + j] > 0.0f) ? 1 : 0;
    lcnt[tid] = c0;
    __syncthreads();
    if (tid == 0) {
        int s = 0;
        for (int k = 0; k < 256; ++k) { int c = lcnt[k]; lcnt[k] = s; s += c; }
        stot = s;
    }
    __syncthreads();
    int off = lcnt[tid];
    for (int j = 0; j < 16; ++j) {
        if (Arow[base + j] > 0.0f) {
            if (off < MAXDEG) sidx[off] = base + j;
            ++off;
        }
    }
    __syncthreads();
    int cnt = stot; if (cnt > MAXDEG) cnt = MAXDEG;
    for (int jj = tid; jj < cnt; jj += 256) sq[jj] = expf(Srow[sidx[jj]]);
    __syncthreads();
    if (tid == 0) {
        float s = 0.0f;
        for (int jj = 0; jj < cnt; ++jj) s += sq[jj];
        ssum = s + 1e-7f;
    }
    __syncthreads();
    for (int jj = tid; jj < cnt; jj += 256) {
        nbr_q[p * MAXDEG + jj]   = sq[jj] / ssum;
        nbr_idx[p * MAXDEG + jj] = sidx[jj];
    }
    if (tid == 0) nbr_cnt[p] = cnt;
}

// ---------------- sequential scan: 1 block, 512 threads ----------------
// thread t: rep = t&3 (k-slice [rep*32,rep*32+32)), d0 = (t>>2)&63 (dims d0, d0+64),
//           r2 = t>>8 (row-half in agg; z_upd row in P4)
__global__ __launch_bounds__(512) void scan_kernel(
    const int* __restrict__ u, const int* __restrict__ v,
    const float* __restrict__ time_diff, const int* __restrict__ neg,
    float* __restrict__ z,
    const int* __restrict__ nbr_cnt, const int* __restrict__ nbr_idx, const float* __restrict__ nbr_q,
    const float* __restrict__ Wh,  const float* __restrict__ bh,
    const float* __restrict__ Wst, const float* __restrict__ bst,
    const float* __restrict__ Wrc, const float* __restrict__ brc,
    const float* __restrict__ Wt,  const float* __restrict__ bt,
    float* __restrict__ ZU, float* __restrict__ ZV,
    float* __restrict__ UNs, float* __restrict__ VNs)
{
    __shared__ float zs[MAXDEG * ZROW];          // 55,296 B, skewed k-slice layout
    __shared__ float zu_s[DD], zv_s[DD];
    __shared__ float h_s[2][DD];
    __shared__ float zupd_s[2][DD];
    __shared__ float q_s[MAXDEG];
    __shared__ float mxp[2][DD];
    __shared__ float tdi_s[8];

    const int t   = threadIdx.x;
    const int rep = t & 3;
    const int d0  = (t >> 2) & 63;
    const int r2  = t >> 8;

    // persistent register weights: W_h rows d0 / d0+64, k-slice rep  (64 VGPRs)
    float4 wh0[8], wh1[8];
    #pragma unroll
    for (int m = 0; m < 8; ++m) {
        wh0[m] = *(const float4*)(Wh + (size_t)d0*DD + rep*32 + m*4);
        wh1[m] = *(const float4*)(Wh + (size_t)(d0+64)*DD + rep*32 + m*4);
    }
    const float4 wt0 = *(const float4*)(Wt + (size_t)d0*4);
    const float4 wt1 = *(const float4*)(Wt + (size_t)(d0+64)*4);
    const float bh0 = bh[d0], bh1 = bh[d0+64];
    const float bs0 = bst[d0] + brc[d0] + bt[d0];
    const float bs1 = bst[d0+64] + brc[d0+64] + bt[d0+64];

    auto agg_side = [&](int side, int cnt) {
        float mx0 = -3.0e38f, mx1 = -3.0e38f;
        #pragma unroll 2
        for (int j = r2; j < cnt; j += 2) {
            const float4* zr = (const float4*)&zs[j*ZROW + rep*36];
            float a0 = 0.f, a1 = 0.f;
            #pragma unroll
            for (int m = 0; m < 8; ++m) {
                float4 zz = zr[m];
                a0 += dot4f(zz, wh0[m]);
                a1 += dot4f(zz, wh1[m]);
            }
            a0 += __shfl_xor(a0, 1); a0 += __shfl_xor(a0, 2);
            a1 += __shfl_xor(a1, 1); a1 += __shfl_xor(a1, 2);
            const float qj = q_s[j];
            mx0 = fmaxf(mx0, qj * (a0 + bh0));
            mx1 = fmaxf(mx1, qj * (a1 + bh1));
        }
        if (rep == 0) { mxp[r2][d0] = mx0; mxp[r2][d0+64] = mx1; }
        __syncthreads();
        if (t < DD) {
            const float mm = fmaxf(mxp[0][t], mxp[1][t]);
            h_s[side][t] = (cnt > 0) ? 1.0f/(1.0f + expf(-mm)) : 0.0f;
        }
        __syncthreads();
    };

    for (int i = 0; i < BB; ++i) {
        const int ui = u[i];
        const int vi = v[i];
        const int p0 = i * 2;
        const int cnt0 = nbr_cnt[p0];      // neighbors of v[i]
        const int cnt1 = nbr_cnt[p0 + 1];  // neighbors of u[i]

        // ---- P0: all reads of pre-update z; stage side 0; captures ----
        if (t < 32) {
            float4 val = *(const float4*)(z + (size_t)ui*DD + t*4);
            *(float4*)&zu_s[t*4] = val;
            *(float4*)(ZU + (size_t)i*DD + t*4) = val;
        } else if (t < 64) {
            int c = t - 32;
            float4 val = *(const float4*)(z + (size_t)vi*DD + c*4);
            *(float4*)&zv_s[c*4] = val;
            *(float4*)(ZV + (size_t)i*DD + c*4) = val;
        } else if (t < 72) {
            const float sd[4] = {50.f, 7.f, 15.f, 15.f};
            tdi_s[t-64] = time_diff[i*8 + (t-64)] / sd[(t-64) & 3];
        }
        if (t < cnt0) q_s[t] = nbr_q[(size_t)p0*MAXDEG + t];
        // negative-sample capture (pre-update z); broadcast halves come from ZU/ZV in lam
        for (int e = t; e < 2*QQ*32; e += 512) {
            int k = e >> 5, c4 = e & 31;
            int nd = neg[i*2*QQ + k];
            float4 val = *(const float4*)(z + (size_t)nd*DD + c4*4);
            if (k < QQ) *(float4*)(VNs + ((size_t)i*QQ + k)*DD + c4*4) = val;
            else        *(float4*)(UNs + ((size_t)i*QQ + (k-QQ))*DD + c4*4) = val;
        }
        // stage side-0 neighbor rows into skewed LDS
        for (int e = t; e < cnt0*32; e += 512) {
            int rr = e >> 5, c4 = e & 31;
            int row = nbr_idx[(size_t)p0*MAXDEG + rr];
            float4 val = *(const float4*)(z + (size_t)row*DD + c4*4);
            *(float4*)&zs[rr*ZROW + (c4>>3)*36 + (c4&7)*4] = val;
        }
        __syncthreads();

        // ---- P1: agg side 0 ----
        agg_side(0, cnt0);

        // ---- P2: stage side 1 ----
        if (t < cnt1) q_s[t] = nbr_q[(size_t)(p0+1)*MAXDEG + t];
        for (int e = t; e < cnt1*32; e += 512) {
            int rr = e >> 5, c4 = e & 31;
            int row = nbr_idx[(size_t)(p0+1)*MAXDEG + rr];
            float4 val = *(const float4*)(z + (size_t)row*DD + c4*4);
            *(float4*)&zs[rr*ZROW + (c4>>3)*36 + (c4&7)*4] = val;
        }
        __syncthreads();

        // ---- P3: agg side 1 ----
        agg_side(1, cnt1);

        // ---- P4: z_upd (r2 picks row; weights streamed from global, L2-hot) ----
        {
            const float* hp = h_s[r2];
            const float* zp = r2 ? zv_s : zu_s;
            const float* wsb0 = Wst + (size_t)d0*DD + rep*32;
            const float* wsb1 = Wst + (size_t)(d0+64)*DD + rep*32;
            const float* wrb0 = Wrc + (size_t)d0*DD + rep*32;
            const float* wrb1 = Wrc + (size_t)(d0+64)*DD + rep*32;
            float a0 = 0.f, a1 = 0.f;
            #pragma unroll
            for (int m = 0; m < 8; ++m) {
                float4 hh = *(const float4*)&hp[rep*32 + m*4];
                float4 zz = *(const float4*)&zp[rep*32 + m*4];
                a0 += dot4f(hh, *(const float4*)(wsb0 + m*4));
                a0 += dot4f(zz, *(const float4*)(wrb0 + m*4));
                a1 += dot4f(hh, *(const float4*)(wsb1 + m*4));
                a1 += dot4f(zz, *(const float4*)(wrb1 + m*4));
            }
            a0 += __shfl_xor(a0, 1); a0 += __shfl_xor(a0, 2);
            a1 += __shfl_xor(a1, 1); a1 += __shfl_xor(a1, 2);
            if (rep == 0) {
                float td0 = tdi_s[r2*4+0]*wt0.x + tdi_s[r2*4+1]*wt0.y
                          + tdi_s[r2*4+2]*wt0.z + tdi_s[r2*4+3]*wt0.w;
                float td1 = tdi_s[r2*4+0]*wt1.x + tdi_s[r2*4+1]*wt1.y
                          + tdi_s[r2*4+2]*wt1.z + tdi_s[r2*4+3]*wt1.w;
                zupd_s[r2][d0]    = 1.0f/(1.0f + expf(-(a0 + bs0 + td0)));
                zupd_s[r2][d0+64] = 1.0f/(1.0f + expf(-(a1 + bs1 + td1)));
            }
        }
        __syncthreads();

        // ---- P5: scatter (vi wins on conflict: same lane stores in order) ----
        if (t < 32) {
            float4 a = *(const float4*)&zupd_s[0][t*4];
            float4 b = *(const float4*)&zupd_s[1][t*4];
            *(float4*)(z + (size_t)ui*DD + t*4) = a;
            *(float4*)(z + (size_t)vi*DD + t*4) = b;
        }
        __threadfence_block();   // cheap: vmcnt drain only; same-CU L1 is coherent
        __syncthreads();
    }
}

// ---------------- intensity epilogue (parallel) ----------------
__global__ void lam_kernel(const float* __restrict__ ZU, const float* __restrict__ ZV,
                           const float* __restrict__ UNs, const float* __restrict__ VNs,
                           const int* __restrict__ et,
                           const float* __restrict__ w0, const float* __restrict__ b0,
                           const float* __restrict__ w1, const float* __restrict__ b1,
                           const float* __restrict__ psi,
                           float* __restrict__ out)
{
    const int b   = blockIdx.x;            // 0..1407
    const int i   = b / 11;
    const int col = b % 11;
    const int l   = threadIdx.x;           // 0..63
    const float* xu;
    const float* xv;
    if (col == 0) { xu = ZU + (size_t)i*DD; xv = ZV + (size_t)i*DD; }
    else {
        int k = col - 1;
        xu = (k < QQ) ? (ZU + (size_t)i*DD) : (UNs + ((size_t)i*QQ + (k-QQ))*DD);
        xv = (k < QQ) ? (VNs + ((size_t)i*QQ + k)*DD) : (ZV + (size_t)i*DD);
    }
    float g0 = xu[l]*w0[l] + xu[l+64]*w0[l+64] + xv[l]*w0[DD+l] + xv[l+64]*w0[DD+l+64];
    float g1 = xu[l]*w1[l] + xu[l+64]*w1[l+64] + xv[l]*w1[DD+l] + xv[l+64]*w1[DD+l+64];
    #pragma unroll
    for (int s = 32; s >= 1; s >>= 1) { g0 += __shfl_xor(g0, s); g1 += __shfl_xor(g1, s); }
    if (l == 0) {
        g0 += b0[0]; g1 += b1[0];
        const float p0 = psi[0], p1 = psi[1];
        float r;
        if (col == 0) {
            int e = et[i];
            float g = e ? g1 : g0;
            float p = e ? p1 : p0;
            float y = g / (p + 1e-7f);
            r = p * (fmaxf(y, 0.f) + log1pf(expf(-fabsf(y))));
        } else {
            float y0 = g0 / (p0 + 1e-7f);
            float y1 = g1 / (p1 + 1e-7f);
            r = p0 * (fmaxf(y0, 0.f) + log1pf(expf(-fabsf(y0))))
              + p1 * (fmaxf(y1, 0.f) + log1pf(expf(-fabsf(y1))));
        }
        out[i*11 + col] = r;
    }
}

extern "C" void kernel_launch(void* const* d_in, const int* in_sizes, int n_in,
                              void* d_out, int out_size, void* d_ws, size_t ws_size,
                              hipStream_t stream)
{
    const int*   u   = (const int*)d_in[0];
    const int*   v   = (const int*)d_in[1];
    const int*   et  = (const int*)d_in[2];
    const float* td  = (const float*)d_in[3];
    const int*   neg = (const int*)d_in[4];
    const float* z0  = (const float*)d_in[5];
    const float* A   = (const float*)d_in[6];
    const float* S   = (const float*)d_in[7];
    const float* w0  = (const float*)d_in[8];
    const float* b0  = (const float*)d_in[9];
    const float* w1  = (const float*)d_in[10];
    const float* b1  = (const float*)d_in[11];
    const float* psi = (const float*)d_in[12];
    const float* Wh  = (const float*)d_in[13];
    const float* bh  = (const float*)d_in[14];
    const float* Wst = (const float*)d_in[15];
    const float* bst = (const float*)d_in[16];
    const float* Wrc = (const float*)d_in[17];
    const float* brc = (const float*)d_in[18];
    const float* Wt  = (const float*)d_in[19];
    const float* bt  = (const float*)d_in[20];

    char* ws = (char*)d_ws;
    size_t off = 0;
    auto alloc = [&](size_t bytes) {
        void* p = ws + off;
        off = (off + bytes + 255) & ~(size_t)255;
        return p;
    };
    float* z    = (float*)alloc((size_t)NN*DD*sizeof(float));
    float* ZU   = (float*)alloc((size_t)BB*DD*sizeof(float));
    float* ZV   = (float*)alloc((size_t)BB*DD*sizeof(float));
    float* UNs  = (float*)alloc((size_t)BB*QQ*DD*sizeof(float));
    float* VNs  = (float*)alloc((size_t)BB*QQ*DD*sizeof(float));
    int*   ncnt = (int*)alloc((size_t)2*BB*sizeof(int));
    int*   nidx = (int*)alloc((size_t)2*BB*MAXDEG*sizeof(int));
    float* nq   = (float*)alloc((size_t)2*BB*MAXDEG*sizeof(float));

    hipMemcpyAsync(z, z0, (size_t)NN*DD*sizeof(float), hipMemcpyDeviceToDevice, stream);
    nbr_kernel<<<2*BB, 256, 0, stream>>>(u, v, A, S, ncnt, nidx, nq);
    scan_kernel<<<1, 512, 0, stream>>>(u, v, td, neg, z, ncnt, nidx, nq,
                                       Wh, bh, Wst, bst, Wrc, brc, Wt, bt,
                                       ZU, ZV, UNs, VNs);
    lam_kernel<<<BB*(1 + 2*QQ), 64, 0, stream>>>(ZU, ZV, UNs, VNs, et,
                                                 w0, b0, w1, b1, psi, (float*)d_out);
}

// Round 3
// 710.958 us; speedup vs baseline: 16.7532x; 4.5300x over previous
//
#include <hip/hip_runtime.h>
#include <hip/hip_bf16.h>

#define NN 4096
#define DD 128
#define BB 128
#define QQ 5
#define MAXDEG 96          // multiple of 16 (MFMA m-tiles)

typedef __attribute__((ext_vector_type(8))) short bf16x8;
typedef __attribute__((ext_vector_type(4))) float f32x4;

__device__ __forceinline__ float dot4f(float4 a, float4 b) {
    return a.x*b.x + a.y*b.y + a.z*b.z + a.w*b.w;
}
// round-to-nearest-even f32 -> bf16 (values are finite; no NaN path needed)
__device__ __forceinline__ short bfr(float x) {
    unsigned u = __float_as_uint(x);
    unsigned r = (u + 0x7fffu + ((u >> 16) & 1u)) >> 16;
    return (short)r;
}

// ---------------- neighbor-list precompute (fully parallel, deterministic) ----------------
__global__ void nbr_kernel(const int* __restrict__ u, const int* __restrict__ v,
                           const float* __restrict__ A, const float* __restrict__ S,
                           int* __restrict__ nbr_cnt, int* __restrict__ nbr_idx,
                           float* __restrict__ nbr_q)
{
    __shared__ int   lcnt[257];
    __shared__ int   sidx[MAXDEG];
    __shared__ float sq[MAXDEG];
    __shared__ float ssum;
    __shared__ int   stot;

    const int p    = blockIdx.x;          // 0..255 : (event i, side)
    const int i    = p >> 1;
    const int side = p & 1;
    const int other = (side == 0) ? v[i] : u[i];   // h_struct[0]=agg(v), h_struct[1]=agg(u)
    const float* Arow = A + (size_t)other * NN;
    const float* Srow = S + (size_t)other * NN;
    const int tid = threadIdx.x;          // 0..255

    const int base = tid * 16;
    int c0 = 0;
    for (int j = 0; j < 16; ++j) c0 += (Arow[base + j] > 0.0f) ? 1 : 0;
    lcnt[tid] = c0;
    __syncthreads();
    if (tid == 0) {
        int s = 0;
        for (int k = 0; k < 256; ++k) { int c = lcnt[k]; lcnt[k] = s; s += c; }
        stot = s;
    }
    __syncthreads();
    int off = lcnt[tid];
    for (int j = 0; j < 16; ++j) {
        if (Arow[base + j] > 0.0f) {
            if (off < MAXDEG) sidx[off] = base + j;
            ++off;
        }
    }
    __syncthreads();
    int cnt = stot; if (cnt > MAXDEG) cnt = MAXDEG;
    for (int jj = tid; jj < cnt; jj += 256) sq[jj] = expf(Srow[sidx[jj]]);
    __syncthreads();
    if (tid == 0) {
        float s = 0.0f;
        for (int jj = 0; jj < cnt; ++jj) s += sq[jj];
        ssum = s + 1e-7f;
    }
    __syncthreads();
    for (int jj = tid; jj < cnt; jj += 256) {
        nbr_q[p * MAXDEG + jj]   = sq[jj] / ssum;
        nbr_idx[p * MAXDEG + jj] = sidx[jj];
    }
    if (tid == 0) nbr_cnt[p] = cnt;
}

// ---------------- sequential scan: 1 block, 512 threads, MFMA agg ----------------
// wave wv (0..7) owns output dims n0 = wv*16 .. +15 in the agg.
// update phase: rep = t&3 (k-slice), d0 = (t>>2)&63 (dims d0,d0+64), r2 = t>>8 (row).
__global__ __launch_bounds__(512) void scan_kernel(
    const int* __restrict__ u, const int* __restrict__ v,
    const float* __restrict__ time_diff, const int* __restrict__ neg,
    float* __restrict__ z,
    const int* __restrict__ nbr_cnt, const int* __restrict__ nbr_idx, const float* __restrict__ nbr_q,
    const float* __restrict__ Wh,  const float* __restrict__ bh,
    const float* __restrict__ Wst, const float* __restrict__ bst,
    const float* __restrict__ Wrc, const float* __restrict__ brc,
    const float* __restrict__ Wt,  const float* __restrict__ bt,
    float* __restrict__ ZU, float* __restrict__ ZV,
    float* __restrict__ UNs, float* __restrict__ VNs)
{
    __shared__ char  zb[2][MAXDEG * 256];     // bf16 rows, XOR-swizzled 16B chunks (49,152 B)
    __shared__ float zu_s[DD], zv_s[DD];
    __shared__ float h_s[2][DD];
    __shared__ float q_s[2][MAXDEG];
    __shared__ float tdi_s[8];

    const int t  = threadIdx.x;
    const int wv = t >> 6;
    const int ln = t & 63;
    const int kg = ln >> 4;                   // k-group 0..3
    const int n_b = wv * 16 + (ln & 15);      // this lane's output dim in agg

    const int rep = t & 3;
    const int d0  = (t >> 2) & 63;
    const int r2  = t >> 8;

    // ---- persistent register weights ----
    // B-fragments of Wh^T for this wave's 16 output dims: whb[kt][j] = Wh[n_b][kt*32+kg*8+j]
    bf16x8 whb[4];
    #pragma unroll
    for (int kt = 0; kt < 4; ++kt) {
        const float* p = Wh + (size_t)n_b * DD + kt * 32 + kg * 8;
        #pragma unroll
        for (int j = 0; j < 8; ++j) whb[kt][j] = bfr(p[j]);
    }
    const float bh_n = bh[n_b];
    const float4 wt0 = *(const float4*)(Wt + (size_t)d0 * 4);
    const float4 wt1 = *(const float4*)(Wt + (size_t)(d0 + 64) * 4);
    const float bs0 = bst[d0]      + brc[d0]      + bt[d0];
    const float bs1 = bst[d0 + 64] + brc[d0 + 64] + bt[d0 + 64];

    // agg for one side: per-wave MFMA over m-tiles, masked max epilogue
    auto agg = [&](int side, int cnt) {
        float mx = -3.0e38f;
        const int mt_n = (cnt + 15) >> 4;
        for (int mt = 0; mt < mt_n; ++mt) {
            f32x4 acc = {0.f, 0.f, 0.f, 0.f};
            const int rowa = mt * 16 + (ln & 15);
            #pragma unroll
            for (int kt = 0; kt < 4; ++kt) {
                const int ch = (kt * 4 + kg) ^ (rowa & 7);
                bf16x8 af = *(const bf16x8*)&zb[side][rowa * 256 + (ch << 4)];
                acc = __builtin_amdgcn_mfma_f32_16x16x32_bf16(af, whb[kt], acc, 0, 0, 0);
            }
            const int mbase = mt * 16 + kg * 4;
            #pragma unroll
            for (int r = 0; r < 4; ++r) {
                const int mg = mbase + r;
                const float g = q_s[side][mg] * (acc[r] + bh_n);
                if (mg < cnt) mx = fmaxf(mx, g);
            }
        }
        mx = fmaxf(mx, __shfl_xor(mx, 16));
        mx = fmaxf(mx, __shfl_xor(mx, 32));
        if (ln < 16) h_s[side][wv * 16 + ln] = (cnt > 0) ? 1.0f / (1.0f + expf(-mx)) : 0.0f;
    };

    for (int i = 0; i < BB; ++i) {
        const int ui = u[i];
        const int vi = v[i];
        const int p0 = i * 2;
        const int cnt0 = nbr_cnt[p0];       // neighbors of v[i] -> h_struct[0]
        const int cnt1 = nbr_cnt[p0 + 1];   // neighbors of u[i] -> h_struct[1]

        // ================= P0: all pre-update-z reads; stage BOTH sides =================
        if (t < 32) {
            float4 val = *(const float4*)(z + (size_t)ui * DD + t * 4);
            *(float4*)&zu_s[t * 4] = val;
            *(float4*)(ZU + (size_t)i * DD + t * 4) = val;
        } else if (t < 64) {
            const int c = t - 32;
            float4 val = *(const float4*)(z + (size_t)vi * DD + c * 4);
            *(float4*)&zv_s[c * 4] = val;
            *(float4*)(ZV + (size_t)i * DD + c * 4) = val;
        } else if (t < 72) {
            const float sd[4] = {50.f, 7.f, 15.f, 15.f};
            tdi_s[t - 64] = time_diff[i * 8 + (t - 64)] / sd[(t - 64) & 3];
        }
        if (t < cnt0) q_s[0][t] = nbr_q[(size_t)p0 * MAXDEG + t];
        else if (t >= 128 && t < 128 + cnt1) q_s[1][t - 128] = nbr_q[(size_t)(p0 + 1) * MAXDEG + (t - 128)];

        // negative-sample capture (f32, straight to global)
        for (int e = t; e < 2 * QQ * 32; e += 512) {
            const int k = e >> 5, c4 = e & 31;
            const int nd = neg[i * 2 * QQ + k];
            float4 val = *(const float4*)(z + (size_t)nd * DD + c4 * 4);
            if (k < QQ) *(float4*)(VNs + ((size_t)i * QQ + k) * DD + c4 * 4) = val;
            else        *(float4*)(UNs + ((size_t)i * QQ + (k - QQ)) * DD + c4 * 4) = val;
        }
        // stage side-0 neighbor rows as swizzled bf16 (16 chunks of 8 dims per row)
        for (int e = t; e < cnt0 * 16; e += 512) {
            const int rr = e >> 4, c = e & 15;
            const int row = nbr_idx[(size_t)p0 * MAXDEG + rr];
            const float* src = z + (size_t)row * DD + c * 8;
            float4 a = *(const float4*)src;
            float4 b = *(const float4*)(src + 4);
            bf16x8 w;
            w[0] = bfr(a.x); w[1] = bfr(a.y); w[2] = bfr(a.z); w[3] = bfr(a.w);
            w[4] = bfr(b.x); w[5] = bfr(b.y); w[6] = bfr(b.z); w[7] = bfr(b.w);
            *(bf16x8*)&zb[0][rr * 256 + ((c ^ (rr & 7)) << 4)] = w;
        }
        // stage side-1 neighbor rows
        for (int e = t; e < cnt1 * 16; e += 512) {
            const int rr = e >> 4, c = e & 15;
            const int row = nbr_idx[(size_t)(p0 + 1) * MAXDEG + rr];
            const float* src = z + (size_t)row * DD + c * 8;
            float4 a = *(const float4*)src;
            float4 b = *(const float4*)(src + 4);
            bf16x8 w;
            w[0] = bfr(a.x); w[1] = bfr(a.y); w[2] = bfr(a.z); w[3] = bfr(a.w);
            w[4] = bfr(b.x); w[5] = bfr(b.y); w[6] = bfr(b.z); w[7] = bfr(b.w);
            *(bf16x8*)&zb[1][rr * 256 + ((c ^ (rr & 7)) << 4)] = w;
        }
        __syncthreads();   // B1

        // ================= P1: MFMA agg, both sides (read-only LDS) =================
        agg(0, cnt0);
        agg(1, cnt1);
        __syncthreads();   // B2

        // ================= P2: z_upd + direct scatter =================
        {
            const float* hp = h_s[r2];
            const float* zp = r2 ? zv_s : zu_s;
            const float* wsb0 = Wst + (size_t)d0 * DD + rep * 32;
            const float* wsb1 = Wst + (size_t)(d0 + 64) * DD + rep * 32;
            const float* wrb0 = Wrc + (size_t)d0 * DD + rep * 32;
            const float* wrb1 = Wrc + (size_t)(d0 + 64) * DD + rep * 32;
            float a0 = 0.f, a1 = 0.f;
            #pragma unroll
            for (int m = 0; m < 8; ++m) {
                float4 hh = *(const float4*)&hp[rep * 32 + m * 4];
                float4 zz = *(const float4*)&zp[rep * 32 + m * 4];
                a0 += dot4f(hh, *(const float4*)(wsb0 + m * 4));
                a0 += dot4f(zz, *(const float4*)(wrb0 + m * 4));
                a1 += dot4f(hh, *(const float4*)(wsb1 + m * 4));
                a1 += dot4f(zz, *(const float4*)(wrb1 + m * 4));
            }
            a0 += __shfl_xor(a0, 1); a0 += __shfl_xor(a0, 2);
            a1 += __shfl_xor(a1, 1); a1 += __shfl_xor(a1, 2);
            if (rep == 0) {
                const float td0 = tdi_s[r2*4+0]*wt0.x + tdi_s[r2*4+1]*wt0.y
                                + tdi_s[r2*4+2]*wt0.z + tdi_s[r2*4+3]*wt0.w;
                const float td1 = tdi_s[r2*4+0]*wt1.x + tdi_s[r2*4+1]*wt1.y
                                + tdi_s[r2*4+2]*wt1.z + tdi_s[r2*4+3]*wt1.w;
                const float o0 = 1.0f / (1.0f + expf(-(a0 + bs0 + td0)));
                const float o1 = 1.0f / (1.0f + expf(-(a1 + bs1 + td1)));
                const int rowi = r2 ? vi : ui;
                if (ui != vi || r2 == 1) {      // reference order: vi's update wins
                    z[(size_t)rowi * DD + d0]      = o0;
                    z[(size_t)rowi * DD + d0 + 64] = o1;
                }
            }
        }
        __threadfence_block();
        __syncthreads();   // B3 (drains scatter before next-step gathers)
    }
}

// ---------------- intensity epilogue (parallel) ----------------
__global__ void lam_kernel(const float* __restrict__ ZU, const float* __restrict__ ZV,
                           const float* __restrict__ UNs, const float* __restrict__ VNs,
                           const int* __restrict__ et,
                           const float* __restrict__ w0, const float* __restrict__ b0,
                           const float* __restrict__ w1, const float* __restrict__ b1,
                           const float* __restrict__ psi,
                           float* __restrict__ out)
{
    const int b   = blockIdx.x;            // 0..1407
    const int i   = b / 11;
    const int col = b % 11;
    const int l   = threadIdx.x;           // 0..63
    const float* xu;
    const float* xv;
    if (col == 0) { xu = ZU + (size_t)i*DD; xv = ZV + (size_t)i*DD; }
    else {
        const int k = col - 1;
        xu = (k < QQ) ? (ZU + (size_t)i*DD) : (UNs + ((size_t)i*QQ + (k-QQ))*DD);
        xv = (k < QQ) ? (VNs + ((size_t)i*QQ + k)*DD) : (ZV + (size_t)i*DD);
    }
    float g0 = xu[l]*w0[l] + xu[l+64]*w0[l+64] + xv[l]*w0[DD+l] + xv[l+64]*w0[DD+l+64];
    float g1 = xu[l]*w1[l] + xu[l+64]*w1[l+64] + xv[l]*w1[DD+l] + xv[l+64]*w1[DD+l+64];
    #pragma unroll
    for (int s = 32; s >= 1; s >>= 1) { g0 += __shfl_xor(g0, s); g1 += __shfl_xor(g1, s); }
    if (l == 0) {
        g0 += b0[0]; g1 += b1[0];
        const float p0 = psi[0], p1 = psi[1];
        float r;
        if (col == 0) {
            const int e = et[i];
            const float g = e ? g1 : g0;
            const float p = e ? p1 : p0;
            const float y = g / (p + 1e-7f);
            r = p * (fmaxf(y, 0.f) + log1pf(expf(-fabsf(y))));
        } else {
            const float y0 = g0 / (p0 + 1e-7f);
            const float y1 = g1 / (p1 + 1e-7f);
            r = p0 * (fmaxf(y0, 0.f) + log1pf(expf(-fabsf(y0))))
              + p1 * (fmaxf(y1, 0.f) + log1pf(expf(-fabsf(y1))));
        }
        out[i*11 + col] = r;
    }
}

extern "C" void kernel_launch(void* const* d_in, const int* in_sizes, int n_in,
                              void* d_out, int out_size, void* d_ws, size_t ws_size,
                              hipStream_t stream)
{
    const int*   u   = (const int*)d_in[0];
    const int*   v   = (const int*)d_in[1];
    const int*   et  = (const int*)d_in[2];
    const float* td  = (const float*)d_in[3];
    const int*   neg = (const int*)d_in[4];
    const float* z0  = (const float*)d_in[5];
    const float* A   = (const float*)d_in[6];
    const float* S   = (const float*)d_in[7];
    const float* w0  = (const float*)d_in[8];
    const float* b0  = (const float*)d_in[9];
    const float* w1  = (const float*)d_in[10];
    const float* b1  = (const float*)d_in[11];
    const float* psi = (const float*)d_in[12];
    const float* Wh  = (const float*)d_in[13];
    const float* bh  = (const float*)d_in[14];
    const float* Wst = (const float*)d_in[15];
    const float* bst = (const float*)d_in[16];
    const float* Wrc = (const float*)d_in[17];
    const float* brc = (const float*)d_in[18];
    const float* Wt  = (const float*)d_in[19];
    const float* bt  = (const float*)d_in[20];

    char* ws = (char*)d_ws;
    size_t off = 0;
    auto alloc = [&](size_t bytes) {
        void* p = ws + off;
        off = (off + bytes + 255) & ~(size_t)255;
        return p;
    };
    float* z    = (float*)alloc((size_t)NN*DD*sizeof(float));
    float* ZU   = (float*)alloc((size_t)BB*DD*sizeof(float));
    float* ZV   = (float*)alloc((size_t)BB*DD*sizeof(float));
    float* UNs  = (float*)alloc((size_t)BB*QQ*DD*sizeof(float));
    float* VNs  = (float*)alloc((size_t)BB*QQ*DD*sizeof(float));
    int*   ncnt = (int*)alloc((size_t)2*BB*sizeof(int));
    int*   nidx = (int*)alloc((size_t)2*BB*MAXDEG*sizeof(int));
    float* nq   = (float*)alloc((size_t)2*BB*MAXDEG*sizeof(float));

    hipMemcpyAsync(z, z0, (size_t)NN*DD*sizeof(float), hipMemcpyDeviceToDevice, stream);
    nbr_kernel<<<2*BB, 256, 0, stream>>>(u, v, A, S, ncnt, nidx, nq);
    scan_kernel<<<1, 512, 0, stream>>>(u, v, td, neg, z, ncnt, nidx, nq,
                                       Wh, bh, Wst, bst, Wrc, brc, Wt, bt,
                                       ZU, ZV, UNs, VNs);
    lam_kernel<<<BB*(1 + 2*QQ), 64, 0, stream>>>(ZU, ZV, UNs, VNs, et,
                                                 w0, b0, w1, b1, psi, (float*)d_out);
}